// Round 1
// baseline (220.115 us; speedup 1.0000x reference)
//
#include <hip/hip_runtime.h>
#include <hip/hip_bf16.h>
#include <stdint.h>

#define M_TOT 8192
#define DIN   1024
#define DEXP  1024
#define NEXP  8

#define BM 128
#define BN 128
#define BK 64

typedef __attribute__((ext_vector_type(8))) short bf16x8;
typedef __attribute__((ext_vector_type(4))) float f32x4;
typedef __attribute__((ext_vector_type(8))) unsigned short us8;

typedef __attribute__((address_space(1))) void* as1vp;
typedef __attribute__((address_space(3))) void* as3vp;

__device__ __forceinline__ unsigned short f2bf(float f) {
    union { float f; unsigned u; } v; v.f = f;
    return (unsigned short)((v.u + 0x7fffu + ((v.u >> 16) & 1u)) >> 16);
}

__device__ __forceinline__ void gl_lds16(const unsigned short* g, unsigned short* l) {
    __builtin_amdgcn_global_load_lds((as1vp)g, (as3vp)l, 16, 0, 0);
}

// ---------------- x fp32 -> bf16 ----------------
__global__ __launch_bounds__(256) void cvt_x_k(const float* __restrict__ in,
                                               unsigned short* __restrict__ out, int n8) {
    int i = blockIdx.x * 256 + threadIdx.x;
    int stride = gridDim.x * 256;
    for (; i < n8; i += stride) {
        const float4* p = (const float4*)in + (size_t)i * 2;
        float4 a = p[0], b = p[1];
        us8 o;
        o[0] = f2bf(a.x); o[1] = f2bf(a.y); o[2] = f2bf(a.z); o[3] = f2bf(a.w);
        o[4] = f2bf(b.x); o[5] = f2bf(b.y); o[6] = f2bf(b.z); o[7] = f2bf(b.w);
        *(us8*)(out + (size_t)i * 8) = o;
    }
}

// ------- We (n, din, dexp) fp32 -> Wt (n, dexp, din) bf16, tiled transpose -------
__global__ __launch_bounds__(256) void cvt_w_k(const float* __restrict__ We,
                                               unsigned short* __restrict__ Wt) {
    __shared__ float tile[64][65];
    int n  = blockIdx.z;
    int k0 = blockIdx.y * 64;   // din index
    int j0 = blockIdx.x * 64;   // dexp index
    int t  = threadIdx.x;
    int tr = t >> 6, tc = t & 63;
    const float* src = We + (size_t)n * DIN * DEXP;
    #pragma unroll
    for (int rr = 0; rr < 16; ++rr) {
        int r = rr * 4 + tr;
        tile[r][tc] = src[(size_t)(k0 + r) * DEXP + j0 + tc];
    }
    __syncthreads();
    unsigned short* dst = Wt + (size_t)n * DEXP * DIN;
    #pragma unroll
    for (int rr = 0; rr < 16; ++rr) {
        int r = rr * 4 + tr;
        dst[(size_t)(j0 + r) * DIN + k0 + tc] = f2bf(tile[tc][r]);
    }
}

// ---------------- gate = softmax(x @ Wg + bg) ----------------
__global__ __launch_bounds__(256) void gate_k(const float* __restrict__ x,
                                              const float* __restrict__ Wg,
                                              const float* __restrict__ bg,
                                              float* __restrict__ gate) {
    __shared__ float wgt[NEXP][DIN];   // transposed for conflict-free reads
    int t = threadIdx.x;
    for (int idx = t; idx < DIN * NEXP; idx += 256)
        wgt[idx & 7][idx >> 3] = Wg[idx];
    __syncthreads();
    int wid = t >> 6, lane = t & 63;
    for (int m = blockIdx.x * 4 + wid; m < M_TOT; m += gridDim.x * 4) {
        const float* xr = x + (size_t)m * DIN;
        float acc[NEXP];
        #pragma unroll
        for (int n = 0; n < NEXP; ++n) acc[n] = 0.f;
        for (int i = 0; i < DIN / 64; ++i) {
            int d = i * 64 + lane;
            float xv = xr[d];
            #pragma unroll
            for (int n = 0; n < NEXP; ++n) acc[n] = fmaf(xv, wgt[n][d], acc[n]);
        }
        #pragma unroll
        for (int n = 0; n < NEXP; ++n) {
            #pragma unroll
            for (int off = 32; off; off >>= 1) acc[n] += __shfl_xor(acc[n], off);
            acc[n] += bg[n];
        }
        float mx = acc[0];
        #pragma unroll
        for (int n = 1; n < NEXP; ++n) mx = fmaxf(mx, acc[n]);
        float s = 0.f, e[NEXP];
        #pragma unroll
        for (int n = 0; n < NEXP; ++n) { e[n] = __expf(acc[n] - mx); s += e[n]; }
        float inv = 1.f / s;
        if (lane < NEXP) gate[(size_t)m * NEXP + lane] = e[lane] * inv;
    }
}

// ---------------- fused MoE GEMM ----------------
// out[m, j] = sum_n gate[m,n] * relu( (Xb @ Wt[n]^T)[m,j] + be[n,j] )
__global__ __launch_bounds__(256, 2) void moe_k(const unsigned short* __restrict__ Xb,
                                                const unsigned short* __restrict__ Wt,
                                                const float* __restrict__ gate,
                                                const float* __restrict__ be,
                                                float* __restrict__ out) {
    __shared__ __align__(16) unsigned short As[BM * BK];  // [128][64]
    __shared__ __align__(16) unsigned short Bs[BN * BK];  // [128][64] (N-major)
    __shared__ float gl[BM * NEXP];                       // gate slice

    int t    = threadIdx.x;
    int nbn  = DEXP / BN;                 // 8
    int brow = ((int)blockIdx.x / nbn) * BM;
    int bcol = ((int)blockIdx.x % nbn) * BN;
    int wid  = t >> 6, lane = t & 63;
    int wm   = wid >> 1, wn = wid & 1;    // 2x2 waves, each 64x64
    int l16  = lane & 15, lk = lane >> 4;

    // stage this block's gate rows: 128*8 floats = 256 float4
    ((float4*)gl)[t] = ((const float4*)(gate + (size_t)brow * NEXP))[t];

    f32x4 acc_out[4][4] = {};

    for (int n = 0; n < NEXP; ++n) {
        f32x4 acc_e[4][4] = {};
        const unsigned short* Wn = Wt + (size_t)n * DEXP * DIN;

        for (int k0 = 0; k0 < DIN; k0 += BK) {
            __syncthreads();   // previous iteration done reading LDS
            #pragma unroll
            for (int i = 0; i < 4; ++i) {
                int e = i * 2048 + t * 8;         // element offset, lane-linear
                int r = e >> 6, c = e & 63;
                gl_lds16(Xb + (size_t)(brow + r) * DIN + k0 + c, As + e);
                gl_lds16(Wn + (size_t)(bcol + r) * DIN + k0 + c, Bs + e);
            }
            __syncthreads();   // staging visible (compiler drains vmcnt)

            #pragma unroll
            for (int ks = 0; ks < 2; ++ks) {
                bf16x8 a[4], b[4];
                #pragma unroll
                for (int mi = 0; mi < 4; ++mi)
                    a[mi] = *(const bf16x8*)&As[(wm * 64 + mi * 16 + l16) * BK + ks * 32 + lk * 8];
                #pragma unroll
                for (int ni = 0; ni < 4; ++ni)
                    b[ni] = *(const bf16x8*)&Bs[(wn * 64 + ni * 16 + l16) * BK + ks * 32 + lk * 8];
                #pragma unroll
                for (int mi = 0; mi < 4; ++mi)
                    #pragma unroll
                    for (int ni = 0; ni < 4; ++ni)
                        acc_e[mi][ni] = __builtin_amdgcn_mfma_f32_16x16x32_bf16(
                            a[mi], b[ni], acc_e[mi][ni], 0, 0, 0);
            }
        }

        // fused epilogue: acc_out += gate * relu(acc_e + be)
        #pragma unroll
        for (int ni = 0; ni < 4; ++ni) {
            int col = bcol + wn * 64 + ni * 16 + l16;
            float bias = be[(size_t)n * DEXP + col];
            #pragma unroll
            for (int mi = 0; mi < 4; ++mi) {
                int rloc = wm * 64 + mi * 16 + lk * 4;
                #pragma unroll
                for (int r = 0; r < 4; ++r) {
                    float g = gl[(rloc + r) * NEXP + n];
                    float h = acc_e[mi][ni][r] + bias;
                    h = fmaxf(h, 0.f);
                    acc_out[mi][ni][r] += g * h;
                }
            }
        }
    }

    // write fp32 output
    #pragma unroll
    for (int mi = 0; mi < 4; ++mi)
        #pragma unroll
        for (int ni = 0; ni < 4; ++ni) {
            int col = bcol + wn * 64 + ni * 16 + l16;
            #pragma unroll
            for (int r = 0; r < 4; ++r) {
                int row = brow + wm * 64 + mi * 16 + lk * 4 + r;
                out[(size_t)row * DEXP + col] = acc_out[mi][ni][r];
            }
        }
}

extern "C" void kernel_launch(void* const* d_in, const int* in_sizes, int n_in,
                              void* d_out, int out_size, void* d_ws, size_t ws_size,
                              hipStream_t stream) {
    const float* x  = (const float*)d_in[0];
    const float* We = (const float*)d_in[1];
    const float* be = (const float*)d_in[2];
    const float* Wg = (const float*)d_in[3];
    const float* bg = (const float*)d_in[4];
    float* out = (float*)d_out;

    unsigned short* Xb = (unsigned short*)d_ws;                    // 16 MiB bf16 x
    unsigned short* Wt = Xb + (size_t)M_TOT * DIN;                 // 16 MiB bf16 We^T
    float* gate = (float*)(Wt + (size_t)NEXP * DEXP * DIN);        // 256 KiB fp32 gate

    hipLaunchKernelGGL(cvt_x_k, dim3(2048), dim3(256), 0, stream, x, Xb, M_TOT * DIN / 8);
    hipLaunchKernelGGL(cvt_w_k, dim3(16, 16, 8), dim3(256), 0, stream, We, Wt);
    hipLaunchKernelGGL(gate_k, dim3(512), dim3(256), 0, stream, x, Wg, bg, gate);
    hipLaunchKernelGGL(moe_k, dim3((M_TOT / BM) * (DEXP / BN)), dim3(256), 0, stream,
                       Xb, Wt, gate, be, out);
}